// Round 4
// baseline (524.028 us; speedup 1.0000x reference)
//
#include <hip/hip_runtime.h>
#include <cstdint>
#include <cstddef>

#define TLEN    50
#define BATCH   16
#define D_IN    512
#define SRC_LEN 200
#define VOCAB   20000
#define CVOCAB  20400

typedef __bf16 bf16x8 __attribute__((ext_vector_type(8)));
typedef float  f32x4  __attribute__((ext_vector_type(4)));

#define GEMM_BLOCKS 625                   // 32 vocab cols per block (2 waves x 16)
#define ZERO_BLOCKS 40
#define SCAN_BLOCKS (SRC_LEN * BATCH)     // 3200
#define NT 128

// ---- kernel 0: p_copy[800] = sigmoid(hidden . Wc + bc); hidden -> bf16 ----
__global__ __launch_bounds__(256)
void pc_kernel(const float* __restrict__ hidden,
               const float* __restrict__ Wc,
               const float* __restrict__ bc,
               float* __restrict__ pc,
               __bf16* __restrict__ hbf)
{
    const int row  = blockIdx.x * 4 + (threadIdx.x >> 6);   // 0..799
    const int lane = threadIdx.x & 63;
    const float* h = hidden + (size_t)row * D_IN + lane * 8;
    float4 h0 = *(const float4*)(h);
    float4 h1 = *(const float4*)(h + 4);
    // bf16 copy of hidden (one 16B store per thread) for the GEMM A-fragments
    bf16x8 hb;
    hb[0] = (__bf16)h0.x; hb[1] = (__bf16)h0.y;
    hb[2] = (__bf16)h0.z; hb[3] = (__bf16)h0.w;
    hb[4] = (__bf16)h1.x; hb[5] = (__bf16)h1.y;
    hb[6] = (__bf16)h1.z; hb[7] = (__bf16)h1.w;
    *(bf16x8*)(hbf + (size_t)row * D_IN + lane * 8) = hb;

    float4 w0 = *(const float4*)(Wc + lane * 8);
    float4 w1 = *(const float4*)(Wc + lane * 8 + 4);
    float s = h0.x*w0.x + h0.y*w0.y + h0.z*w0.z + h0.w*w0.w
            + h1.x*w1.x + h1.y*w1.y + h1.z*w1.z + h1.w*w1.w;
    #pragma unroll
    for (int o = 1; o < 64; o <<= 1) s += __shfl_xor(s, o);
    if (lane == 0) pc[row] = 1.0f / (1.0f + __expf(-(s + bc[0])));
}

// ---- kernel 1: fused GEMM+softmax / tail-zero / src_map scan --------------
// Roles: [0,625) GEMM (LDS-free, barrier-free), [625,665) zero, [665,3865) scan.
__global__ __launch_bounds__(NT)
void fused_main(const __bf16* __restrict__ hbf,
                const float* __restrict__ src_map,
                const float* __restrict__ W,
                const float* __restrict__ pc,
                float* __restrict__ out,
                int* __restrict__ src_ids)
{
    const int bid = blockIdx.x;
    const int tid = threadIdx.x;

    if (bid < GEMM_BLOCKS) {
        // ---- GEMM (logits, bf16 MFMA) + softmax over batch + (1-pc) scale ----
        // b[v] bias is uniform along the softmax (batch) axis -> cancels; unused.
        const int lane = tid & 63;
        const int wv   = tid >> 6;            // 0..1
        const int l15  = lane & 15;
        const int q    = lane >> 4;
        const int colbase = bid * 32 + wv * 16;   // 625*32 == 20000 exactly

        // B fragments: 16 cols x 512 k = 64 VGPRs. Loaded ONCE from HBM, then
        // PINNED via empty asm so LLVM cannot sink the loads into the t-loop
        // (R2 pathology: VGPR=80 proved W was being re-read 25x from L3).
        bf16x8 bfrag[16];
        {
            const float* wrow = W + (size_t)(colbase + l15) * D_IN + q * 8;
            #pragma unroll
            for (int c = 0; c < 16; ++c) {
                float4 f0 = *(const float4*)(wrow + c * 32);
                float4 f1 = *(const float4*)(wrow + c * 32 + 4);
                bf16x8 bf;
                bf[0] = (__bf16)f0.x; bf[1] = (__bf16)f0.y;
                bf[2] = (__bf16)f0.z; bf[3] = (__bf16)f0.w;
                bf[4] = (__bf16)f1.x; bf[5] = (__bf16)f1.y;
                bf[6] = (__bf16)f1.z; bf[7] = (__bf16)f1.w;
                bfrag[c] = bf;
            }
            #pragma unroll
            for (int c = 0; c < 16; ++c) {
                f32x4 t = *(f32x4*)&bfrag[c];
                asm volatile("" : "+v"(t));
                bfrag[c] = *(bf16x8*)&t;
            }
        }

        for (int t = 0; t < TLEN; ++t) {
            // A fragments direct from the bf16 hidden copy (L2-resident, 0.8MB).
            // Per wave-load: 64 lanes fetch 16 fully-consumed 64B lines.
            const __bf16* arow = hbf + ((size_t)t * BATCH + l15) * D_IN + q * 8;
            f32x4 accA = {0.f, 0.f, 0.f, 0.f};
            f32x4 accB = {0.f, 0.f, 0.f, 0.f};
            #pragma unroll
            for (int c = 0; c < 16; c += 2) {
                bf16x8 a0 = *(const bf16x8*)(arow + c * 32);
                bf16x8 a1 = *(const bf16x8*)(arow + c * 32 + 32);
                accA = __builtin_amdgcn_mfma_f32_16x16x32_bf16(a0, bfrag[c],     accA, 0, 0, 0);
                accB = __builtin_amdgcn_mfma_f32_16x16x32_bf16(a1, bfrag[c + 1], accB, 0, 0, 0);
            }
            f32x4 acc = accA + accB;

            float4 pc4 = *(const float4*)(pc + t * 16 + q * 4);

            // softmax over batch (the D rows), b==1 masked to prob 0
            float mx = -INFINITY;
            #pragma unroll
            for (int r = 0; r < 4; ++r)
                if (q * 4 + r != 1) mx = fmaxf(mx, acc[r]);
            mx = fmaxf(mx, __shfl_xor(mx, 16));
            mx = fmaxf(mx, __shfl_xor(mx, 32));
            float e[4], s = 0.f;
            #pragma unroll
            for (int r = 0; r < 4; ++r) {
                e[r] = (q * 4 + r == 1) ? 0.f : __expf(acc[r] - mx);
                s += e[r];
            }
            s += __shfl_xor(s, 16);
            s += __shfl_xor(s, 32);
            const float inv = 1.0f / s;
            const int v = colbase + l15;
            #pragma unroll
            for (int r = 0; r < 4; ++r) {
                const int b = q * 4 + r;
                out[(size_t)(t * BATCH + b) * CVOCAB + v] = e[r] * inv * (1.0f - pc4[r]);
            }
        }
    } else if (bid < GEMM_BLOCKS + ZERO_BLOCKS) {
        // ---- zero extended-vocab tail cols [20000,20400) of all 800 rows ----
        const int zb = bid - GEMM_BLOCKS;
        const float4 z = {0.f, 0.f, 0.f, 0.f};
        for (int i = tid; i < 2000; i += NT) {
            const int f = zb * 2000 + i;          // 0..79999 float4s, 100 per row
            const int r = f / 100;
            const int c = f % 100;
            *(float4*)(out + (size_t)r * CVOCAB + VOCAB + c * 4) = z;
        }
    } else {
        // ---- scan one one-hot src_map row (20400 fp32) -> index ----
        const int row = bid - GEMM_BLOCKS - ZERO_BLOCKS;   // (s*16+b)
        const float4* base = (const float4*)(src_map + (size_t)row * CVOCAB);
        int found = -1;
        for (int i0 = tid; i0 < 1275; i0 += NT) {
            float4 x0 = base[i0];
            float4 x1 = base[i0 + 1275];
            float4 x2 = base[i0 + 2550];
            float4 x3 = base[i0 + 3825];
            #pragma unroll
            for (int seg = 0; seg < 4; ++seg) {
                float4 x = seg == 0 ? x0 : seg == 1 ? x1 : seg == 2 ? x2 : x3;
                const int e0 = (i0 + seg * 1275) * 4;
                if (x.x > 0.5f) found = e0;
                if (x.y > 0.5f) found = e0 + 1;
                if (x.z > 0.5f) found = e0 + 2;
                if (x.w > 0.5f) found = e0 + 3;
            }
        }
        if (found >= 0) src_ids[row] = found;     // exactly one finder per row
    }
}

// ---- kernel 2: scatter copy-probs -----------------------------------------
// r=t*16+b; reference's split/stack/transpose sends copy_prob[t,b,:] to
// output row (t'=r%50, b'=r/50). atomicAdd onto already-written out_prob.
__global__ __launch_bounds__(256)
void scatter_copy(const float* __restrict__ attn,
                  const float* __restrict__ pc,
                  const int* __restrict__ src_ids,
                  float* __restrict__ out)
{
    const int p  = blockIdx.x;             // 0..799
    const int si = threadIdx.x;
    if (si >= SRC_LEN) return;
    const int b  = p & 15;
    const size_t obase = (size_t)((p % TLEN) * BATCH + (p / TLEN)) * CVOCAB;
    const int id = src_ids[si * BATCH + b];
    const float val = attn[(size_t)p * SRC_LEN + si] * pc[p];
    if ((unsigned)id < (unsigned)CVOCAB)
        atomicAdd(out + obase + id, val);
}

extern "C" void kernel_launch(void* const* d_in, const int* in_sizes, int n_in,
                              void* d_out, int out_size, void* d_ws, size_t ws_size,
                              hipStream_t stream)
{
    const float* hidden  = (const float*)d_in[0];  // (50,16,512)
    const float* attn    = (const float*)d_in[1];  // (50,16,200)
    const float* src_map = (const float*)d_in[2];  // (200,16,20400) one-hot
    const float* W       = (const float*)d_in[3];  // (20000,512)
    // d_in[4] = b (20000): cancels in softmax over batch -> unused
    const float* Wc      = (const float*)d_in[5];  // (1,512)
    const float* bc      = (const float*)d_in[6];  // (1,)
    float* out   = (float*)d_out;                  // (50,16,20400)

    int*    src_ids = (int*)d_ws;                         // [0, 12800) bytes
    float*  pc      = (float*)((char*)d_ws + 12800);      // [12800, 16000)
    __bf16* hbf     = (__bf16*)((char*)d_ws + 16000);     // 800*512*2 B

    pc_kernel<<<dim3(200), dim3(256), 0, stream>>>(hidden, Wc, bc, pc, hbf);
    fused_main<<<dim3(GEMM_BLOCKS + ZERO_BLOCKS + SCAN_BLOCKS), dim3(NT), 0, stream>>>(
        hbf, src_map, W, pc, out, src_ids);
    scatter_copy<<<dim3(TLEN * BATCH), dim3(256), 0, stream>>>(attn, pc, src_ids, out);
}

// Round 5
// 464.152 us; speedup vs baseline: 1.1290x; 1.1290x over previous
//
#include <hip/hip_runtime.h>
#include <cstdint>
#include <cstddef>

#define TLEN    50
#define BATCH   16
#define D_IN    512
#define SRC_LEN 200
#define VOCAB   20000
#define CVOCAB  20400

typedef __bf16 bf16x8 __attribute__((ext_vector_type(8)));
typedef float  f32x4  __attribute__((ext_vector_type(4)));

#define GEMM_BLOCKS 625                   // 32 vocab cols per block; 625*32 == 20000
#define ZERO_BLOCKS 40
#define SCAN_BLOCKS (SRC_LEN * BATCH)     // 3200
#define NT 256                            // 4 waves; waves split the t-range

// ---- kernel 0: p_copy[800] = sigmoid(hidden . Wc + bc); hidden -> bf16 ----
__global__ __launch_bounds__(256)
void pc_kernel(const float* __restrict__ hidden,
               const float* __restrict__ Wc,
               const float* __restrict__ bc,
               float* __restrict__ pc,
               __bf16* __restrict__ hbf)
{
    const int row  = blockIdx.x * 4 + (threadIdx.x >> 6);   // 0..799
    const int lane = threadIdx.x & 63;
    const float* h = hidden + (size_t)row * D_IN + lane * 8;
    float4 h0 = *(const float4*)(h);
    float4 h1 = *(const float4*)(h + 4);
    bf16x8 hb;
    hb[0] = (__bf16)h0.x; hb[1] = (__bf16)h0.y;
    hb[2] = (__bf16)h0.z; hb[3] = (__bf16)h0.w;
    hb[4] = (__bf16)h1.x; hb[5] = (__bf16)h1.y;
    hb[6] = (__bf16)h1.z; hb[7] = (__bf16)h1.w;
    *(bf16x8*)(hbf + (size_t)row * D_IN + lane * 8) = hb;

    float4 w0 = *(const float4*)(Wc + lane * 8);
    float4 w1 = *(const float4*)(Wc + lane * 8 + 4);
    float s = h0.x*w0.x + h0.y*w0.y + h0.z*w0.z + h0.w*w0.w
            + h1.x*w1.x + h1.y*w1.y + h1.z*w1.z + h1.w*w1.w;
    #pragma unroll
    for (int o = 1; o < 64; o <<= 1) s += __shfl_xor(s, o);
    if (lane == 0) pc[row] = 1.0f / (1.0f + __expf(-(s + bc[0])));
}

// ---- kernel 1: fused GEMM+softmax / tail-zero / src_map scan --------------
// Roles: [0,625) GEMM, [625,665) zero, [665,3865) scan.
// GEMM: B tile (32 cols x 512) in LDS in EXACT fragment order -> each lane's
// B-frag is one ds_read_b128 at an immediate offset: zero bank conflicts,
// zero address math, no VGPR residency battle (R2/R4 pathology).
__global__ __launch_bounds__(NT)
void fused_main(const __bf16* __restrict__ hbf,
                const float* __restrict__ src_map,
                const float* __restrict__ W,
                const float* __restrict__ pc,
                float* __restrict__ out,
                int* __restrict__ src_ids)
{
    const int bid = blockIdx.x;
    const int tid = threadIdx.x;

    if (bid < GEMM_BLOCKS) {
        // b[v] bias is uniform along the softmax (batch) axis -> cancels; unused.
        __shared__ __align__(16) __bf16 Blds[2 * 16 * 64 * 8];  // 32 KB

        const int lane = tid & 63;
        const int wv   = tid >> 6;            // wave 0..3 -> t-range split
        const int l15  = lane & 15;
        const int q    = lane >> 4;
        const int colbase = bid * 32;

        // --- stage B: 32 (g,c) fragment-planes, 8 per wave, frag order ---
        {
            #pragma unroll
            for (int j = 0; j < 8; ++j) {
                const int p = wv * 8 + j;      // 0..31
                const int g = p >> 4;          // col group 0..1
                const int c = p & 15;          // k chunk 0..15
                const float* src = W + (size_t)(colbase + g * 16 + l15) * D_IN
                                     + q * 8 + c * 32;
                float4 f0 = *(const float4*)(src);
                float4 f1 = *(const float4*)(src + 4);
                bf16x8 bf;
                bf[0] = (__bf16)f0.x; bf[1] = (__bf16)f0.y;
                bf[2] = (__bf16)f0.z; bf[3] = (__bf16)f0.w;
                bf[4] = (__bf16)f1.x; bf[5] = (__bf16)f1.y;
                bf[6] = (__bf16)f1.z; bf[7] = (__bf16)f1.w;
                *(bf16x8*)(Blds + (size_t)(g * 16 + c) * 512 + lane * 8) = bf;
            }
        }
        __syncthreads();   // the ONLY barrier

        // --- t-loop: waves split [0,50) as 13/13/12/12; iterations independent ---
        const int tb0 = wv * 12 + (wv < 2 ? wv : 2);          // {0,13,26,38}
        const int tb1 = tb0 + (wv < 2 ? 13 : 12);             // {13,26,38,50}

        for (int t = tb0; t < tb1; ++t) {
            const __bf16* arow = hbf + ((size_t)t * BATCH + l15) * D_IN + q * 8;
            f32x4 acc0 = {0.f, 0.f, 0.f, 0.f};
            f32x4 acc1 = {0.f, 0.f, 0.f, 0.f};
            #pragma unroll
            for (int c = 0; c < 16; ++c) {
                bf16x8 af = *(const bf16x8*)(arow + c * 32);
                bf16x8 b0 = *(const bf16x8*)(Blds + (size_t)c * 512 + lane * 8);
                bf16x8 b1 = *(const bf16x8*)(Blds + (size_t)(16 + c) * 512 + lane * 8);
                acc0 = __builtin_amdgcn_mfma_f32_16x16x32_bf16(af, b0, acc0, 0, 0, 0);
                acc1 = __builtin_amdgcn_mfma_f32_16x16x32_bf16(af, b1, acc1, 0, 0, 0);
            }

            float4 pc4 = *(const float4*)(pc + t * 16 + q * 4);

            // softmax over batch (C rows), b==1 masked to prob 0, x(1-pc)
            #pragma unroll
            for (int g = 0; g < 2; ++g) {
                f32x4 acc = g ? acc1 : acc0;
                float mx = -INFINITY;
                #pragma unroll
                for (int r = 0; r < 4; ++r)
                    if (q * 4 + r != 1) mx = fmaxf(mx, acc[r]);
                mx = fmaxf(mx, __shfl_xor(mx, 16));
                mx = fmaxf(mx, __shfl_xor(mx, 32));
                float e[4], s = 0.f;
                #pragma unroll
                for (int r = 0; r < 4; ++r) {
                    e[r] = (q * 4 + r == 1) ? 0.f : __expf(acc[r] - mx);
                    s += e[r];
                }
                s += __shfl_xor(s, 16);
                s += __shfl_xor(s, 32);
                const float inv = 1.0f / s;
                const int v = colbase + g * 16 + l15;
                #pragma unroll
                for (int r = 0; r < 4; ++r) {
                    const int b = q * 4 + r;
                    out[(size_t)(t * BATCH + b) * CVOCAB + v] =
                        e[r] * inv * (1.0f - pc4[r]);
                }
            }
        }
    } else if (bid < GEMM_BLOCKS + ZERO_BLOCKS) {
        // ---- zero extended-vocab tail cols [20000,20400) of all 800 rows ----
        const int zb = bid - GEMM_BLOCKS;
        const float4 z = {0.f, 0.f, 0.f, 0.f};
        for (int i = tid; i < 2000; i += NT) {
            const int f = zb * 2000 + i;          // 0..79999 float4s, 100 per row
            const int r = f / 100;
            const int c = f % 100;
            *(float4*)(out + (size_t)r * CVOCAB + VOCAB + c * 4) = z;
        }
    } else {
        // ---- scan one one-hot src_map row (20400 fp32) -> index ----
        const int row = bid - GEMM_BLOCKS - ZERO_BLOCKS;   // (s*16+b)
        const float4* base = (const float4*)(src_map + (size_t)row * CVOCAB);
        int found = -1;
        for (int i0 = tid; i0 < 1275; i0 += NT) {
            float4 x0 = base[i0];
            float4 x1 = base[i0 + 1275];
            float4 x2 = base[i0 + 2550];
            float4 x3 = base[i0 + 3825];
            #pragma unroll
            for (int seg = 0; seg < 4; ++seg) {
                float4 x = seg == 0 ? x0 : seg == 1 ? x1 : seg == 2 ? x2 : x3;
                const int e0 = (i0 + seg * 1275) * 4;
                if (x.x > 0.5f) found = e0;
                if (x.y > 0.5f) found = e0 + 1;
                if (x.z > 0.5f) found = e0 + 2;
                if (x.w > 0.5f) found = e0 + 3;
            }
        }
        if (found >= 0) src_ids[row] = found;     // exactly one finder per row
    }
}

// ---- kernel 2: scatter copy-probs -----------------------------------------
// r=t*16+b; reference's split/stack/transpose sends copy_prob[t,b,:] to
// output row (t'=r%50, b'=r/50). atomicAdd onto already-written out_prob.
__global__ __launch_bounds__(256)
void scatter_copy(const float* __restrict__ attn,
                  const float* __restrict__ pc,
                  const int* __restrict__ src_ids,
                  float* __restrict__ out)
{
    const int p  = blockIdx.x;             // 0..799
    const int si = threadIdx.x;
    if (si >= SRC_LEN) return;
    const int b  = p & 15;
    const size_t obase = (size_t)((p % TLEN) * BATCH + (p / TLEN)) * CVOCAB;
    const int id = src_ids[si * BATCH + b];
    const float val = attn[(size_t)p * SRC_LEN + si] * pc[p];
    if ((unsigned)id < (unsigned)CVOCAB)
        atomicAdd(out + obase + id, val);
}

extern "C" void kernel_launch(void* const* d_in, const int* in_sizes, int n_in,
                              void* d_out, int out_size, void* d_ws, size_t ws_size,
                              hipStream_t stream)
{
    const float* hidden  = (const float*)d_in[0];  // (50,16,512)
    const float* attn    = (const float*)d_in[1];  // (50,16,200)
    const float* src_map = (const float*)d_in[2];  // (200,16,20400) one-hot
    const float* W       = (const float*)d_in[3];  // (20000,512)
    // d_in[4] = b (20000): cancels in softmax over batch -> unused
    const float* Wc      = (const float*)d_in[5];  // (1,512)
    const float* bc      = (const float*)d_in[6];  // (1,)
    float* out   = (float*)d_out;                  // (50,16,20400)

    int*    src_ids = (int*)d_ws;                         // [0, 12800) bytes
    float*  pc      = (float*)((char*)d_ws + 12800);      // [12800, 16000)
    __bf16* hbf     = (__bf16*)((char*)d_ws + 16000);     // 800*512*2 B

    pc_kernel<<<dim3(200), dim3(256), 0, stream>>>(hidden, Wc, bc, pc, hbf);
    fused_main<<<dim3(GEMM_BLOCKS + ZERO_BLOCKS + SCAN_BLOCKS), dim3(NT), 0, stream>>>(
        hbf, src_map, W, pc, out, src_ids);
    scatter_copy<<<dim3(TLEN * BATCH), dim3(256), 0, stream>>>(attn, pc, src_ids, out);
}